// Round 8
// baseline (777.570 us; speedup 1.0000x reference)
//
#include <hip/hip_runtime.h>

#define DIM 128
#define NLEV 8
#define NB_STAGE 512           // stage-kernel grid; 4 waves/block -> 2048 wave-slots
#define NSLOT (NB_STAGE * 4)
#define CAP (2 * NSLOT)        // max nodes per class handled (expected ~1213)

// packed-weight offsets (float2 units): [k][jl] -> (W[k][jl], W[k][jl+64])
#define AS_OFF 0
#define UA_OFF 8192            // 256 rows -> 16384
#define NS_OFF 24576
#define UN_OFF 32768
#define MU_OFF 40960
#define WT_OFF 49152
#define PACK_TOTAL 57344

__device__ __forceinline__ int cls_of(int g, int l) {
    if (l < 1 || l > NLEV) return -1;
    if (g == 1) return l - 1;
    if (g == 2) return NLEV + (l - 1);
    return -1;
}

// ---------------- prep kernels ----------------

__global__ void deg_count_kernel(const int* __restrict__ dstv, int* __restrict__ degi, int E) {
    int i = blockIdx.x * blockDim.x + threadIdx.x;
    if (i < E) atomicAdd(&degi[dstv[i]], 1);
}

__global__ void deg_finalize_kernel(const int* __restrict__ degi, float* __restrict__ dis,
                                    float* __restrict__ inv, int n) {
    int i = blockIdx.x * blockDim.x + threadIdx.x;
    if (i < n) {
        float d = (float)degi[i] + 1.0f;
        dis[i] = rsqrtf(d);
        inv[i] = 1.0f / d;
    }
}

// pack 6 weight matrices into float2-paired layout for fast LDS staging
__global__ void pack_kernel(const float* __restrict__ as_w, const float* __restrict__ ua_w,
                            const float* __restrict__ ns_w, const float* __restrict__ un_w,
                            const float* __restrict__ mu_w, const float* __restrict__ wt_w,
                            float2* __restrict__ wpack) {
    int i = blockIdx.x * 256 + threadIdx.x;
    if (i >= PACK_TOTAL) return;
    const float* src;
    int local;
    if (i < UA_OFF)      { src = as_w; local = i; }
    else if (i < NS_OFF) { src = ua_w; local = i - UA_OFF; }
    else if (i < UN_OFF) { src = ns_w; local = i - NS_OFF; }
    else if (i < MU_OFF) { src = un_w; local = i - UN_OFF; }
    else if (i < WT_OFF) { src = mu_w; local = i - MU_OFF; }
    else                 { src = wt_w; local = i - WT_OFF; }
    int k = local >> 6, jl = local & 63;
    wpack[i] = make_float2(src[k * DIM + jl], src[k * DIM + jl + 64]);
}

// ---- 3-kernel parallel exclusive scan: degi[0..n) -> offs[0..n] ----
__global__ __launch_bounds__(1024) void scan1_kernel(const int* __restrict__ degi,
                                                     int* __restrict__ offs,
                                                     int* __restrict__ bsum) {
    __shared__ int sh[1024];
    const int gid = blockIdx.x * 1024 + threadIdx.x;
    const int v = degi[gid];
    sh[threadIdx.x] = v;
    __syncthreads();
    for (int off = 1; off < 1024; off <<= 1) {
        int t = (threadIdx.x >= off) ? sh[threadIdx.x - off] : 0;
        __syncthreads();
        sh[threadIdx.x] += t;
        __syncthreads();
    }
    offs[gid] = sh[threadIdx.x] - v;
    if (threadIdx.x == 1023) bsum[blockIdx.x] = sh[1023];
}

__global__ void scan2_kernel(int* __restrict__ bsum, int nb) {
    const int lane = threadIdx.x & 63;
    const int orig = (lane < nb) ? bsum[lane] : 0;
    int v = orig;
#pragma unroll
    for (int off = 1; off < 64; off <<= 1) {
        int t = __shfl_up(v, off, 64);
        if (lane >= off) v += t;
    }
    if (lane < nb) bsum[lane] = v - orig;
    if (lane == nb - 1) bsum[nb] = v;
}

__global__ __launch_bounds__(1024) void scan3_kernel(int* __restrict__ offs,
                                                     const int* __restrict__ bsum, int n) {
    const int gid = blockIdx.x * 1024 + threadIdx.x;
    offs[gid] += bsum[blockIdx.x];
    if (gid == n - 1) offs[n] = bsum[gridDim.x];
}

__global__ void csr_fill_kernel(const int* __restrict__ srcv, const int* __restrict__ dstv,
                                const int* __restrict__ offs, int* __restrict__ cursor,
                                int* __restrict__ csr_src, int E) {
    int i = blockIdx.x * blockDim.x + threadIdx.x;
    if (i >= E) return;
    int d = dstv[i];
    int pos = offs[d] + atomicAdd(&cursor[d], 1);
    csr_src[pos] = srcv[i];
}

// class lists + per-node packed (cls<<16)|idx lookup (clsidx pre-memset to -1)
__global__ __launch_bounds__(256) void build_node_lists_kernel(const int* __restrict__ gate,
                                                               const int* __restrict__ level,
                                                               int* __restrict__ nlist,
                                                               int* __restrict__ ncnt,
                                                               int* __restrict__ clsidx, int n) {
    __shared__ int lcnt[16];
    __shared__ int lbase[16];
    int t = threadIdx.x;
    int i = blockIdx.x * 256 + t;
    if (t < 16) lcnt[t] = 0;
    __syncthreads();
    int c = -1, lpos = 0;
    if (i < n) {
        c = cls_of(gate[i], level[i]);
        if (c >= 0) lpos = atomicAdd(&lcnt[c], 1);
    }
    __syncthreads();
    if (t < 16 && lcnt[t] > 0) lbase[t] = atomicAdd(&ncnt[t], lcnt[t]);
    __syncthreads();
    if (c >= 0) {
        int idx = lbase[c] + lpos;
        nlist[c * n + idx] = i;
        clsidx[i] = (c << 16) | idx;
    }
}

// ---------------- dense matmul: LDS tile, 64 rows/block, W-prefetch ----------------
template <int BIAS>
__global__ __launch_bounds__(256) void mm_kernel(const float* __restrict__ in0,
                                                 const float* __restrict__ W,
                                                 const float* __restrict__ b,
                                                 float* __restrict__ out, int n) {
    const int R = 64;
    __shared__ float tile[R * DIM];
    const size_t row0 = (size_t)blockIdx.x * R;
    for (int t = threadIdx.x; t < R * DIM / 4; t += 256)
        ((float4*)tile)[t] = ((const float4*)(in0 + row0 * DIM))[t];
    __syncthreads();
    const int g = threadIdx.x >> 7;   // row-half 0/1 (32 rows each)
    const int j = threadIdx.x & 127;  // output column
    float acc[32];
#pragma unroll
    for (int r = 0; r < 32; r++) acc[r] = 0.f;
    const float* tb = tile + (g * 32) * DIM;
    float w0 = W[0 * DIM + j], w1 = W[1 * DIM + j], w2 = W[2 * DIM + j], w3 = W[3 * DIM + j];
    for (int k = 0; k < DIM; k += 4) {
        const int kn = (k + 4 < DIM) ? (k + 4) : 0;  // prefetch next iteration's W
        const float nw0 = W[(kn + 0) * DIM + j];
        const float nw1 = W[(kn + 1) * DIM + j];
        const float nw2 = W[(kn + 2) * DIM + j];
        const float nw3 = W[(kn + 3) * DIM + j];
#pragma unroll
        for (int r = 0; r < 32; r++) {
            const float4 a = *reinterpret_cast<const float4*>(tb + r * DIM + k);
            acc[r] = fmaf(a.x, w0, acc[r]);
            acc[r] = fmaf(a.y, w1, acc[r]);
            acc[r] = fmaf(a.z, w2, acc[r]);
            acc[r] = fmaf(a.w, w3, acc[r]);
        }
        w0 = nw0; w1 = nw1; w2 = nw2; w3 = nw3;
    }
    float bias = BIAS ? b[j] : 0.f;
#pragma unroll
    for (int r = 0; r < 32; r++) out[(row0 + g * 32 + r) * DIM + j] = acc[r] + bias;
}

// ---------------- shared helpers for wave-per-node kernels ----------------

// copy a packed 64KB W (8192 float2) into LDS, fully coalesced float4
__device__ __forceinline__ void stage_pk(const float2* __restrict__ Wp, float2* __restrict__ W2) {
    const float4* s = (const float4*)Wp;
    float4* d = (float4*)W2;
    for (int t = threadIdx.x; t < 4096; t += 256) d[t] = s[t];
}

template <bool MERGE>
__device__ __forceinline__ const float* resolve_row(const float* __restrict__ base,
                                                    const float* __restrict__ tmp,
                                                    const int* __restrict__ clsidx,
                                                    int mcls, int s) {
    if (MERGE) {
        int cc = clsidx[s];
        if ((cc >> 16) == mcls && (cc & 0xFFFF) < CAP) return tmp + (size_t)(cc & 0xFFFF) * DIM;
    }
    return base + (size_t)s * DIM;
}

// wave gathers sum over in-edges of relu(row(src) @ W2 + b); 2-edge unroll
template <bool MERGE>
__device__ __forceinline__ void gather_node(const float* __restrict__ hs,
                                            const float* __restrict__ tmp,
                                            const int* __restrict__ clsidx, int mcls,
                                            const float2* __restrict__ W2,
                                            float bj0, float bj1,
                                            const int* __restrict__ csr_src,
                                            int e0, int e1, int lane,
                                            float& acc0, float& acc1) {
    for (int p = e0; p < e1; p += 2) {
        const bool two = (p + 1 < e1);
        const int s0 = csr_src[p];
        const int s1 = two ? csr_src[p + 1] : s0;
        const float* r0 = resolve_row<MERGE>(hs, tmp, clsidx, mcls, s0);
        const float* r1 = resolve_row<MERGE>(hs, tmp, clsidx, mcls, s1);
        float a00 = r0[lane], a01 = r0[lane + 64];
        float a10 = r1[lane], a11 = r1[lane + 64];
        float m00 = bj0, m01 = bj1, m10 = bj0, m11 = bj1;
#pragma unroll 8
        for (int k = 0; k < 64; k++) {
            float2 w = W2[k * 64 + lane];
            float v0 = __shfl(a00, k, 64);
            float v1 = __shfl(a10, k, 64);
            m00 = fmaf(v0, w.x, m00); m01 = fmaf(v0, w.y, m01);
            m10 = fmaf(v1, w.x, m10); m11 = fmaf(v1, w.y, m11);
        }
#pragma unroll 8
        for (int k = 0; k < 64; k++) {
            float2 w = W2[(k + 64) * 64 + lane];
            float v0 = __shfl(a01, k, 64);
            float v1 = __shfl(a11, k, 64);
            m00 = fmaf(v0, w.x, m00); m01 = fmaf(v0, w.y, m01);
            m10 = fmaf(v1, w.x, m10); m11 = fmaf(v1, w.y, m11);
        }
        acc0 += fmaxf(m00, 0.f);
        acc1 += fmaxf(m01, 0.f);
        if (two) { acc0 += fmaxf(m10, 0.f); acc1 += fmaxf(m11, 0.f); }
    }
}

// ---------------- fused GCN aggregate + mu matmul (wave-per-node, 2-node pairing) ----------------
__global__ __launch_bounds__(256) void gcn_mu_kernel(
        const float* __restrict__ x, const float* __restrict__ dis,
        const float* __restrict__ inv, const float* __restrict__ gb,
        const float2* __restrict__ Wp, const float* __restrict__ mu_b,
        const int* __restrict__ offs, const int* __restrict__ csr_src,
        float* __restrict__ hs, int n) {
    __shared__ float2 W2[128 * 64];
    stage_pk(Wp, W2);
    __syncthreads();
    const int lane = threadIdx.x & 63;
    const int gslot = (blockIdx.x << 2) | (threadIdx.x >> 6);
    const int nsl = gridDim.x << 2;
    const float gb0 = gb[lane], gb1 = gb[lane + 64];
    const float mb0 = mu_b[lane], mb1 = mu_b[lane + 64];
    for (int base = gslot; base < n; base += 2 * nsl) {
        const int na = base;
        const int nb = base + nsl;
        const bool hb = nb < n;
        float a0a, a1a, a0b = 0.f, a1b = 0.f;
        {
            const float iv = inv[na];
            a0a = fmaf(iv, x[(size_t)na * DIM + lane], gb0);
            a1a = fmaf(iv, x[(size_t)na * DIM + lane + 64], gb1);
            const float dn = dis[na];
            const int e1 = offs[na + 1];
            for (int p = offs[na]; p < e1; p++) {
                const int s = csr_src[p];
                const float c = dn * dis[s];
                a0a = fmaf(c, x[(size_t)s * DIM + lane], a0a);
                a1a = fmaf(c, x[(size_t)s * DIM + lane + 64], a1a);
            }
        }
        if (hb) {
            const float iv = inv[nb];
            a0b = fmaf(iv, x[(size_t)nb * DIM + lane], gb0);
            a1b = fmaf(iv, x[(size_t)nb * DIM + lane + 64], gb1);
            const float dn = dis[nb];
            const int e1 = offs[nb + 1];
            for (int p = offs[nb]; p < e1; p++) {
                const int s = csr_src[p];
                const float c = dn * dis[s];
                a0b = fmaf(c, x[(size_t)s * DIM + lane], a0b);
                a1b = fmaf(c, x[(size_t)s * DIM + lane + 64], a1b);
            }
        }
        float u0a = mb0, u1a = mb1, u0b = mb0, u1b = mb1;
#pragma unroll 8
        for (int k = 0; k < 64; k++) {     // one W read feeds both nodes (4 fma / read)
            const float2 w = W2[k * 64 + lane];
            const float va = __shfl(a0a, k, 64);
            const float vb = __shfl(a0b, k, 64);
            u0a = fmaf(va, w.x, u0a); u1a = fmaf(va, w.y, u1a);
            u0b = fmaf(vb, w.x, u0b); u1b = fmaf(vb, w.y, u1b);
        }
#pragma unroll 8
        for (int k = 0; k < 64; k++) {
            const float2 w = W2[(k + 64) * 64 + lane];
            const float va = __shfl(a1a, k, 64);
            const float vb = __shfl(a1b, k, 64);
            u0a = fmaf(va, w.x, u0a); u1a = fmaf(va, w.y, u1a);
            u0b = fmaf(vb, w.x, u0b); u1b = fmaf(vb, w.y, u1b);
        }
        hs[(size_t)na * DIM + lane] = u0a;
        hs[(size_t)na * DIM + lane + 64] = u1a;
        if (hb) {
            hs[(size_t)nb * DIM + lane] = u0b;
            hs[(size_t)nb * DIM + lane + 64] = u1b;
        }
    }
}

// ---------------- level-stage kernels (packed-W staging) ----------------

// AND stage: commit tmpN(cNp)->hs ; agg = gather(as_w, merged w/ tmpN) ;
//            tmpA[idx] = relu( cat[hs[node], agg] @ ua_w + ua_b )
template <bool MERGE>
__global__ __launch_bounds__(256) void and_stage_kernel(
        float* __restrict__ hs, const float* __restrict__ tmpN, float* __restrict__ tmpA,
        const int* __restrict__ offs, const int* __restrict__ csr_src,
        const int* __restrict__ nlist, const int* __restrict__ ncnt,
        const int* __restrict__ clsidx, const float2* __restrict__ wpack,
        const float* __restrict__ as_b, const float* __restrict__ ua_b,
        int cA, int cNp, int n) {
    const int cnt = min(ncnt[cA], CAP);
    const int cntp = MERGE ? min(ncnt[cNp], CAP) : 0;
    const int lim = max(cnt, cntp);
    if ((int)blockIdx.x * 4 >= lim) return;
    __shared__ float2 W2[128 * 64];
    const int lane = threadIdx.x & 63;
    const int gslot = (blockIdx.x << 2) | (threadIdx.x >> 6);
    stage_pk(wpack + AS_OFF, W2);
    if (MERGE) {
        for (int idx = gslot; idx < cntp; idx += NSLOT) {
            const int node = nlist[cNp * n + idx];
            hs[(size_t)node * DIM + lane] = tmpN[(size_t)idx * DIM + lane];
            hs[(size_t)node * DIM + lane + 64] = tmpN[(size_t)idx * DIM + lane + 64];
        }
    }
    __syncthreads();
    const float bj_as0 = as_b[lane], bj_as1 = as_b[lane + 64];
    float ag0[2] = {0.f, 0.f}, ag1[2] = {0.f, 0.f};
    float h0[2] = {0.f, 0.f}, h1[2] = {0.f, 0.f};
    bool act[2];
#pragma unroll
    for (int it = 0; it < 2; it++) {
        const int idx = gslot + it * NSLOT;
        act[it] = idx < cnt;
        if (act[it]) {
            const int nd = nlist[cA * n + idx];
            gather_node<MERGE>(hs, tmpN, clsidx, cNp, W2, bj_as0, bj_as1, csr_src,
                               offs[nd], offs[nd + 1], lane, ag0[it], ag1[it]);
            h0[it] = hs[(size_t)nd * DIM + lane];
            h1[it] = hs[(size_t)nd * DIM + lane + 64];
        }
    }
    float u0[2], u1[2];
    u0[0] = ua_b[lane]; u1[0] = ua_b[lane + 64];
    u0[1] = u0[0]; u1[1] = u1[0];
    __syncthreads();
    stage_pk(wpack + UA_OFF, W2);          // rows 0..127 (hs half)
    __syncthreads();
#pragma unroll
    for (int it = 0; it < 2; it++) {
        if (!act[it]) continue;
#pragma unroll 8
        for (int k = 0; k < 64; k++) {
            float2 w = W2[k * 64 + lane];
            float v = __shfl(h0[it], k, 64);
            u0[it] = fmaf(v, w.x, u0[it]); u1[it] = fmaf(v, w.y, u1[it]);
        }
#pragma unroll 8
        for (int k = 0; k < 64; k++) {
            float2 w = W2[(k + 64) * 64 + lane];
            float v = __shfl(h1[it], k, 64);
            u0[it] = fmaf(v, w.x, u0[it]); u1[it] = fmaf(v, w.y, u1[it]);
        }
    }
    __syncthreads();
    stage_pk(wpack + UA_OFF + 8192, W2);   // rows 128..255 (agg half)
    __syncthreads();
#pragma unroll
    for (int it = 0; it < 2; it++) {
        if (!act[it]) continue;
#pragma unroll 8
        for (int k = 0; k < 64; k++) {
            float2 w = W2[k * 64 + lane];
            float v = __shfl(ag0[it], k, 64);
            u0[it] = fmaf(v, w.x, u0[it]); u1[it] = fmaf(v, w.y, u1[it]);
        }
#pragma unroll 8
        for (int k = 0; k < 64; k++) {
            float2 w = W2[(k + 64) * 64 + lane];
            float v = __shfl(ag1[it], k, 64);
            u0[it] = fmaf(v, w.x, u0[it]); u1[it] = fmaf(v, w.y, u1[it]);
        }
        const int idx = gslot + it * NSLOT;
        tmpA[(size_t)idx * DIM + lane] = fmaxf(u0[it], 0.f);
        tmpA[(size_t)idx * DIM + lane + 64] = fmaxf(u1[it], 0.f);
    }
}

// NOT stage: commit tmpA(cA)->hs ; agg = gather(ns_w, merged w/ tmpA) ;
//            tmpN[idx] = tanh( agg @ un_w + un_b )
__global__ __launch_bounds__(256) void not_stage_kernel(
        float* __restrict__ hs, const float* __restrict__ tmpA, float* __restrict__ tmpN,
        const int* __restrict__ offs, const int* __restrict__ csr_src,
        const int* __restrict__ nlist, const int* __restrict__ ncnt,
        const int* __restrict__ clsidx, const float2* __restrict__ wpack,
        const float* __restrict__ ns_b, const float* __restrict__ un_b,
        int cA, int cN, int n) {
    const int cnt = min(ncnt[cN], CAP);
    const int cntA = min(ncnt[cA], CAP);
    const int lim = max(cnt, cntA);
    if ((int)blockIdx.x * 4 >= lim) return;
    __shared__ float2 W2[128 * 64];
    const int lane = threadIdx.x & 63;
    const int gslot = (blockIdx.x << 2) | (threadIdx.x >> 6);
    stage_pk(wpack + NS_OFF, W2);
    for (int idx = gslot; idx < cntA; idx += NSLOT) {
        const int node = nlist[cA * n + idx];
        hs[(size_t)node * DIM + lane] = tmpA[(size_t)idx * DIM + lane];
        hs[(size_t)node * DIM + lane + 64] = tmpA[(size_t)idx * DIM + lane + 64];
    }
    __syncthreads();
    const float bj_ns0 = ns_b[lane], bj_ns1 = ns_b[lane + 64];
    float ag0[2] = {0.f, 0.f}, ag1[2] = {0.f, 0.f};
    bool act[2];
#pragma unroll
    for (int it = 0; it < 2; it++) {
        const int idx = gslot + it * NSLOT;
        act[it] = idx < cnt;
        if (act[it]) {
            const int nd = nlist[cN * n + idx];
            gather_node<true>(hs, tmpA, clsidx, cA, W2, bj_ns0, bj_ns1, csr_src,
                              offs[nd], offs[nd + 1], lane, ag0[it], ag1[it]);
        }
    }
    float u0[2], u1[2];
    u0[0] = un_b[lane]; u1[0] = un_b[lane + 64];
    u0[1] = u0[0]; u1[1] = u1[0];
    __syncthreads();
    stage_pk(wpack + UN_OFF, W2);
    __syncthreads();
#pragma unroll
    for (int it = 0; it < 2; it++) {
        if (!act[it]) continue;
#pragma unroll 8
        for (int k = 0; k < 64; k++) {
            float2 w = W2[k * 64 + lane];
            float v = __shfl(ag0[it], k, 64);
            u0[it] = fmaf(v, w.x, u0[it]); u1[it] = fmaf(v, w.y, u1[it]);
        }
#pragma unroll 8
        for (int k = 0; k < 64; k++) {
            float2 w = W2[(k + 64) * 64 + lane];
            float v = __shfl(ag1[it], k, 64);
            u0[it] = fmaf(v, w.x, u0[it]); u1[it] = fmaf(v, w.y, u1[it]);
        }
        const int idx = gslot + it * NSLOT;
        tmpN[(size_t)idx * DIM + lane] = tanhf(u0[it]);
        tmpN[(size_t)idx * DIM + lane + 64] = tanhf(u1[it]);
    }
}

// final commit of last level's tmpN -> hs
__global__ __launch_bounds__(256) void commit_kernel(float* __restrict__ hs,
                                                     const float* __restrict__ tmp,
                                                     const int* __restrict__ nlist,
                                                     const int* __restrict__ ncnt,
                                                     int c, int n) {
    const int lane = threadIdx.x & 63;
    const int gslot = (blockIdx.x << 2) | (threadIdx.x >> 6);
    const int cnt = min(ncnt[c], CAP);
    for (int idx = gslot; idx < cnt; idx += NSLOT) {
        const int node = nlist[c * n + idx];
        hs[(size_t)node * DIM + lane] = tmp[(size_t)idx * DIM + lane];
        hs[(size_t)node * DIM + lane + 64] = tmp[(size_t)idx * DIM + lane + 64];
    }
}

// ---------------- fused decoder: zt = hs@Wt in-wave + weighted gather of zs ----------------
__global__ __launch_bounds__(256) void dec_fused_kernel(
        const float* __restrict__ hs, const float* __restrict__ zs,
        const float2* __restrict__ Wp, const int* __restrict__ offs,
        const int* __restrict__ csr_src, float* __restrict__ hf_out, int n) {
    __shared__ float2 W2[128 * 64];
    stage_pk(Wp, W2);
    __syncthreads();
    const int lane = threadIdx.x & 63;
    const int gslot = (blockIdx.x << 2) | (threadIdx.x >> 6);
    const int nsl = gridDim.x << 2;
    for (int base = gslot; base < n; base += 2 * nsl) {
        const int na = base;
        const int nb = base + nsl;
        const bool hb = nb < n;
        float h0a = hs[(size_t)na * DIM + lane];
        float h1a = hs[(size_t)na * DIM + lane + 64];
        float h0b = 0.f, h1b = 0.f;
        if (hb) {
            h0b = hs[(size_t)nb * DIM + lane];
            h1b = hs[(size_t)nb * DIM + lane + 64];
        }
        float b0a = 0.f, b1a = 0.f, b0b = 0.f, b1b = 0.f;
#pragma unroll 8
        for (int k = 0; k < 64; k++) {
            const float2 w = W2[k * 64 + lane];
            const float va = __shfl(h0a, k, 64);
            const float vb = __shfl(h0b, k, 64);
            b0a = fmaf(va, w.x, b0a); b1a = fmaf(va, w.y, b1a);
            b0b = fmaf(vb, w.x, b0b); b1b = fmaf(vb, w.y, b1b);
        }
#pragma unroll 8
        for (int k = 0; k < 64; k++) {
            const float2 w = W2[(k + 64) * 64 + lane];
            const float va = __shfl(h1a, k, 64);
            const float vb = __shfl(h1b, k, 64);
            b0a = fmaf(va, w.x, b0a); b1a = fmaf(va, w.y, b1a);
            b0b = fmaf(vb, w.x, b0b); b1b = fmaf(vb, w.y, b1b);
        }
        {
            float acc0 = 0.f, acc1 = 0.f;
            const int e1 = offs[na + 1];
            for (int p = offs[na]; p < e1; p++) {
                const int s = csr_src[p];
                const float a0 = zs[(size_t)s * DIM + lane];
                const float a1 = zs[(size_t)s * DIM + lane + 64];
                float pd = a0 * b0a + a1 * b1a;
#pragma unroll
                for (int off = 32; off > 0; off >>= 1) pd += __shfl_xor(pd, off, 64);
                const float wg = 1.f / (1.f + __expf(-pd));
                acc0 = fmaf(wg, a0, acc0);
                acc1 = fmaf(wg, a1, acc1);
            }
            hf_out[(size_t)na * DIM + lane] = acc0;
            hf_out[(size_t)na * DIM + lane + 64] = acc1;
        }
        if (hb) {
            float acc0 = 0.f, acc1 = 0.f;
            const int e1 = offs[nb + 1];
            for (int p = offs[nb]; p < e1; p++) {
                const int s = csr_src[p];
                const float a0 = zs[(size_t)s * DIM + lane];
                const float a1 = zs[(size_t)s * DIM + lane + 64];
                float pd = a0 * b0b + a1 * b1b;
#pragma unroll
                for (int off = 32; off > 0; off >>= 1) pd += __shfl_xor(pd, off, 64);
                const float wg = 1.f / (1.f + __expf(-pd));
                acc0 = fmaf(wg, a0, acc0);
                acc1 = fmaf(wg, a1, acc1);
            }
            hf_out[(size_t)nb * DIM + lane] = acc0;
            hf_out[(size_t)nb * DIM + lane + 64] = acc1;
        }
    }
}

extern "C" void kernel_launch(void* const* d_in, const int* in_sizes, int n_in,
                              void* d_out, int out_size, void* d_ws, size_t ws_size,
                              hipStream_t stream) {
    const float* hs_init = (const float*)d_in[0];
    const int* ei = (const int*)d_in[1];
    const int* gate = (const int*)d_in[2];
    const int* level = (const int*)d_in[3];
    const float* gcn_w = (const float*)d_in[4];
    const float* gcn_b = (const float*)d_in[5];
    const float* mu_w = (const float*)d_in[6];
    const float* mu_b = (const float*)d_in[7];
    // ls_w/ls_b (8,9) dead (eval mode); af/nf (14..17) dead (level-loop hf never feeds hs;
    // decoder rebuilds hf from hs alone).
    const float* as_w = (const float*)d_in[10];
    const float* as_b = (const float*)d_in[11];
    const float* ns_w = (const float*)d_in[12];
    const float* ns_b = (const float*)d_in[13];
    const float* ua_w = (const float*)d_in[18];
    const float* ua_b = (const float*)d_in[19];
    const float* un_w = (const float*)d_in[20];
    const float* un_b = (const float*)d_in[21];
    const float* dec_ws_w = (const float*)d_in[22];
    const float* dec_wt_w = (const float*)d_in[23];

    const int n = in_sizes[0] / DIM;  // 32768
    const int E = in_sizes[1] / 2;    // 65536
    const int* srcv = ei;
    const int* dstv = ei + E;

    float* hs = (float*)d_out;             // [n, DIM]
    float* hf_out = hs + (size_t)n * DIM;  // [n, DIM]

    char* wp = (char*)d_ws;
    float* x = (float*)wp;      wp += (size_t)n * DIM * 4;     // gcn tmp, later zs
    float* tmpA = (float*)wp;   wp += (size_t)CAP * DIM * 4;   // AND-update staging
    float* tmpN = (float*)wp;   wp += (size_t)CAP * DIM * 4;   // NOT-update staging
    float2* wpack = (float2*)wp; wp += (size_t)PACK_TOTAL * 8; // packed weights
    char* small0 = wp;
    int* degi = (int*)wp;   wp += (size_t)n * 4;
    int* cursor = (int*)wp; wp += (size_t)n * 4;
    int* ncnt = (int*)wp;   wp += 16 * 4;
    size_t small_bytes = (size_t)(wp - small0);
    int* bsum = (int*)wp;    wp += 64 * 4;
    int* offs = (int*)wp;    wp += (size_t)(n + 1) * 4;
    int* csr_src = (int*)wp; wp += (size_t)E * 4;
    int* nlist = (int*)wp;   wp += (size_t)16 * n * 4;
    int* clsidx = (int*)wp;  wp += (size_t)n * 4;
    float* dis = (float*)wp; wp += (size_t)n * 4;
    float* inv = (float*)wp; wp += (size_t)n * 4;

    hipMemsetAsync(small0, 0, small_bytes, stream);
    hipMemsetAsync(clsidx, 0xFF, (size_t)n * 4, stream);

    pack_kernel<<<(PACK_TOTAL + 255) / 256, 256, 0, stream>>>(as_w, ua_w, ns_w, un_w, mu_w,
                                                              dec_wt_w, wpack);
    deg_count_kernel<<<(E + 255) / 256, 256, 0, stream>>>(dstv, degi, E);
    deg_finalize_kernel<<<(n + 255) / 256, 256, 0, stream>>>(degi, dis, inv, n);
    build_node_lists_kernel<<<(n + 255) / 256, 256, 0, stream>>>(gate, level, nlist, ncnt, clsidx, n);
    scan1_kernel<<<n / 1024, 1024, 0, stream>>>(degi, offs, bsum);
    scan2_kernel<<<1, 64, 0, stream>>>(bsum, n / 1024);
    scan3_kernel<<<n / 1024, 1024, 0, stream>>>(offs, bsum, n);
    csr_fill_kernel<<<(E + 255) / 256, 256, 0, stream>>>(srcv, dstv, offs, cursor, csr_src, E);

    // --- GCN encoder: x = hs_init@gcn_w ; hs = (gather(x)+self+b) @ mu_w + mu_b ---
    mm_kernel<0><<<n / 64, 256, 0, stream>>>(hs_init, gcn_w, nullptr, x, n);
    gcn_mu_kernel<<<512, 256, 0, stream>>>(x, dis, inv, gcn_b, wpack + MU_OFF, mu_b,
                                           offs, csr_src, hs, n);

    // --- level loop: 2 launches/level, 1 final commit ---
    for (int l = 1; l <= NLEV; l++) {
        const int cA = l - 1;
        const int cN = NLEV + l - 1;
        const int cNp = NLEV + l - 2;
        if (l == 1)
            and_stage_kernel<false><<<NB_STAGE, 256, 0, stream>>>(
                hs, tmpN, tmpA, offs, csr_src, nlist, ncnt, clsidx, wpack,
                as_b, ua_b, cA, -9, n);
        else
            and_stage_kernel<true><<<NB_STAGE, 256, 0, stream>>>(
                hs, tmpN, tmpA, offs, csr_src, nlist, ncnt, clsidx, wpack,
                as_b, ua_b, cA, cNp, n);
        not_stage_kernel<<<NB_STAGE, 256, 0, stream>>>(
            hs, tmpA, tmpN, offs, csr_src, nlist, ncnt, clsidx, wpack,
            ns_b, un_b, cA, cN, n);
    }
    commit_kernel<<<NB_STAGE, 256, 0, stream>>>(hs, tmpN, nlist, ncnt, 2 * NLEV - 1, n);

    // --- decoder: zs = hs@dec_ws (dense) ; fused zt + weighted gather ---
    float* zs = x;
    mm_kernel<0><<<n / 64, 256, 0, stream>>>(hs, dec_ws_w, nullptr, zs, n);
    dec_fused_kernel<<<512, 256, 0, stream>>>(hs, zs, wpack + WT_OFF, offs, csr_src, hf_out, n);
}

// Round 9
// 701.693 us; speedup vs baseline: 1.1081x; 1.1081x over previous
//
#include <hip/hip_runtime.h>

#define DIM 128
#define NLEV 8
#define NB_STAGE 512           // stage-kernel grid; 4 waves/block -> 2048 wave-slots
#define NSLOT (NB_STAGE * 4)
#define CAP (2 * NSLOT)        // max nodes per class handled (expected ~1213)

// packed-weight offsets (float2 units): [k][jl] -> (W[k][jl], W[k][jl+64])
#define AS_OFF 0
#define UA_OFF 8192            // 256 rows -> 16384
#define NS_OFF 24576
#define UN_OFF 32768
#define PACK_TOTAL 40960

__device__ __forceinline__ int cls_of(int g, int l) {
    if (l < 1 || l > NLEV) return -1;
    if (g == 1) return l - 1;
    if (g == 2) return NLEV + (l - 1);
    return -1;
}

// ---------------- prep kernels ----------------

__global__ void deg_count_kernel(const int* __restrict__ dstv, int* __restrict__ degi, int E) {
    int i = blockIdx.x * blockDim.x + threadIdx.x;
    if (i < E) atomicAdd(&degi[dstv[i]], 1);
}

__global__ void deg_finalize_kernel(const int* __restrict__ degi, float* __restrict__ dis,
                                    float* __restrict__ inv, int n) {
    int i = blockIdx.x * blockDim.x + threadIdx.x;
    if (i < n) {
        float d = (float)degi[i] + 1.0f;
        dis[i] = rsqrtf(d);
        inv[i] = 1.0f / d;
    }
}

// pack 4 stage weight matrices into float2-paired layout for fast LDS staging
__global__ void pack_kernel(const float* __restrict__ as_w, const float* __restrict__ ua_w,
                            const float* __restrict__ ns_w, const float* __restrict__ un_w,
                            float2* __restrict__ wpack) {
    int i = blockIdx.x * 256 + threadIdx.x;
    if (i >= PACK_TOTAL) return;
    const float* src;
    int local;
    if (i < UA_OFF)      { src = as_w; local = i; }
    else if (i < NS_OFF) { src = ua_w; local = i - UA_OFF; }
    else if (i < UN_OFF) { src = ns_w; local = i - NS_OFF; }
    else                 { src = un_w; local = i - UN_OFF; }
    int k = local >> 6, jl = local & 63;
    wpack[i] = make_float2(src[k * DIM + jl], src[k * DIM + jl + 64]);
}

// ---- 3-kernel parallel exclusive scan: degi[0..n) -> offs[0..n] ----
__global__ __launch_bounds__(1024) void scan1_kernel(const int* __restrict__ degi,
                                                     int* __restrict__ offs,
                                                     int* __restrict__ bsum) {
    __shared__ int sh[1024];
    const int gid = blockIdx.x * 1024 + threadIdx.x;
    const int v = degi[gid];
    sh[threadIdx.x] = v;
    __syncthreads();
    for (int off = 1; off < 1024; off <<= 1) {
        int t = (threadIdx.x >= off) ? sh[threadIdx.x - off] : 0;
        __syncthreads();
        sh[threadIdx.x] += t;
        __syncthreads();
    }
    offs[gid] = sh[threadIdx.x] - v;
    if (threadIdx.x == 1023) bsum[blockIdx.x] = sh[1023];
}

__global__ void scan2_kernel(int* __restrict__ bsum, int nb) {
    const int lane = threadIdx.x & 63;
    const int orig = (lane < nb) ? bsum[lane] : 0;
    int v = orig;
#pragma unroll
    for (int off = 1; off < 64; off <<= 1) {
        int t = __shfl_up(v, off, 64);
        if (lane >= off) v += t;
    }
    if (lane < nb) bsum[lane] = v - orig;
    if (lane == nb - 1) bsum[nb] = v;
}

__global__ __launch_bounds__(1024) void scan3_kernel(int* __restrict__ offs,
                                                     const int* __restrict__ bsum, int n) {
    const int gid = blockIdx.x * 1024 + threadIdx.x;
    offs[gid] += bsum[blockIdx.x];
    if (gid == n - 1) offs[n] = bsum[gridDim.x];
}

__global__ void csr_fill_kernel(const int* __restrict__ srcv, const int* __restrict__ dstv,
                                const int* __restrict__ offs, int* __restrict__ cursor,
                                int* __restrict__ csr_src, int E) {
    int i = blockIdx.x * blockDim.x + threadIdx.x;
    if (i >= E) return;
    int d = dstv[i];
    int pos = offs[d] + atomicAdd(&cursor[d], 1);
    csr_src[pos] = srcv[i];
}

// class lists + per-node packed (cls<<16)|idx lookup (clsidx pre-memset to -1)
__global__ __launch_bounds__(256) void build_node_lists_kernel(const int* __restrict__ gate,
                                                               const int* __restrict__ level,
                                                               int* __restrict__ nlist,
                                                               int* __restrict__ ncnt,
                                                               int* __restrict__ clsidx, int n) {
    __shared__ int lcnt[16];
    __shared__ int lbase[16];
    int t = threadIdx.x;
    int i = blockIdx.x * 256 + t;
    if (t < 16) lcnt[t] = 0;
    __syncthreads();
    int c = -1, lpos = 0;
    if (i < n) {
        c = cls_of(gate[i], level[i]);
        if (c >= 0) lpos = atomicAdd(&lcnt[c], 1);
    }
    __syncthreads();
    if (t < 16 && lcnt[t] > 0) lbase[t] = atomicAdd(&ncnt[t], lcnt[t]);
    __syncthreads();
    if (c >= 0) {
        int idx = lbase[c] + lpos;
        nlist[c * n + idx] = i;
        clsidx[i] = (c << 16) | idx;
    }
}

// ---------------- dense matmul: LDS tile, 64 rows/block, W-prefetch ----------------
template <int BIAS>
__global__ __launch_bounds__(256) void mm_kernel(const float* __restrict__ in0,
                                                 const float* __restrict__ W,
                                                 const float* __restrict__ b,
                                                 float* __restrict__ out, int n) {
    const int R = 64;
    __shared__ float tile[R * DIM];
    const size_t row0 = (size_t)blockIdx.x * R;
    for (int t = threadIdx.x; t < R * DIM / 4; t += 256)
        ((float4*)tile)[t] = ((const float4*)(in0 + row0 * DIM))[t];
    __syncthreads();
    const int g = threadIdx.x >> 7;   // row-half 0/1 (32 rows each)
    const int j = threadIdx.x & 127;  // output column
    float acc[32];
#pragma unroll
    for (int r = 0; r < 32; r++) acc[r] = 0.f;
    const float* tb = tile + (g * 32) * DIM;
    float w0 = W[0 * DIM + j], w1 = W[1 * DIM + j], w2 = W[2 * DIM + j], w3 = W[3 * DIM + j];
    for (int k = 0; k < DIM; k += 4) {
        const int kn = (k + 4 < DIM) ? (k + 4) : 0;  // prefetch next iteration's W
        const float nw0 = W[(kn + 0) * DIM + j];
        const float nw1 = W[(kn + 1) * DIM + j];
        const float nw2 = W[(kn + 2) * DIM + j];
        const float nw3 = W[(kn + 3) * DIM + j];
#pragma unroll
        for (int r = 0; r < 32; r++) {
            const float4 a = *reinterpret_cast<const float4*>(tb + r * DIM + k);
            acc[r] = fmaf(a.x, w0, acc[r]);
            acc[r] = fmaf(a.y, w1, acc[r]);
            acc[r] = fmaf(a.z, w2, acc[r]);
            acc[r] = fmaf(a.w, w3, acc[r]);
        }
        w0 = nw0; w1 = nw1; w2 = nw2; w3 = nw3;
    }
    float bias = BIAS ? b[j] : 0.f;
#pragma unroll
    for (int r = 0; r < 32; r++) out[(row0 + g * 32 + r) * DIM + j] = acc[r] + bias;
}

// fused decoder matmul: zs = in0 @ Ws, zt = in0 @ Wt (shared tile, W-prefetch)
__global__ __launch_bounds__(256) void mm2_kernel(const float* __restrict__ in0,
                                                  const float* __restrict__ Ws,
                                                  const float* __restrict__ Wt,
                                                  float* __restrict__ zs,
                                                  float* __restrict__ zt, int n) {
    const int R = 32;
    __shared__ float tile[R * DIM];
    const size_t row0 = (size_t)blockIdx.x * R;
    for (int t = threadIdx.x; t < R * DIM / 4; t += 256)
        ((float4*)tile)[t] = ((const float4*)(in0 + row0 * DIM))[t];
    __syncthreads();
    const int g = threadIdx.x >> 7;
    const int j = threadIdx.x & 127;
    float accs[16], acct[16];
#pragma unroll
    for (int r = 0; r < 16; r++) { accs[r] = 0.f; acct[r] = 0.f; }
    const float* tb = tile + (g * 16) * DIM;
    float s0 = Ws[0 * DIM + j], s1 = Ws[1 * DIM + j];
    float t0 = Wt[0 * DIM + j], t1 = Wt[1 * DIM + j];
    for (int k = 0; k < DIM; k += 2) {
        const int kn = (k + 2 < DIM) ? (k + 2) : 0;  // prefetch
        const float ns0 = Ws[(kn + 0) * DIM + j];
        const float ns1 = Ws[(kn + 1) * DIM + j];
        const float nt0 = Wt[(kn + 0) * DIM + j];
        const float nt1 = Wt[(kn + 1) * DIM + j];
#pragma unroll
        for (int r = 0; r < 16; r++) {
            const float2 a = *reinterpret_cast<const float2*>(tb + r * DIM + k);
            accs[r] = fmaf(a.x, s0, accs[r]);
            accs[r] = fmaf(a.y, s1, accs[r]);
            acct[r] = fmaf(a.x, t0, acct[r]);
            acct[r] = fmaf(a.y, t1, acct[r]);
        }
        s0 = ns0; s1 = ns1; t0 = nt0; t1 = nt1;
    }
#pragma unroll
    for (int r = 0; r < 16; r++) {
        zs[(row0 + g * 16 + r) * DIM + j] = accs[r];
        zt[(row0 + g * 16 + r) * DIM + j] = acct[r];
    }
}

// ---------------- GCN aggregate as gather ----------------
__global__ __launch_bounds__(256) void gcn_gather_kernel(const float* __restrict__ x,
                                                         const float* __restrict__ dis,
                                                         const float* __restrict__ inv,
                                                         const float* __restrict__ gb,
                                                         const int* __restrict__ offs,
                                                         const int* __restrict__ csr_src,
                                                         float* __restrict__ x2, int n) {
    int slot = threadIdx.x >> 7, j = threadIdx.x & 127;
    for (int node = blockIdx.x * 2 + slot; node < n; node += gridDim.x * 2) {
        float di = dis[node];
        float acc = inv[node] * x[(size_t)node * DIM + j] + gb[j];
        int e1 = offs[node + 1];
        for (int p = offs[node]; p < e1; p++) {
            int s = csr_src[p];
            acc += di * dis[s] * x[(size_t)s * DIM + j];
        }
        x2[(size_t)node * DIM + j] = acc;
    }
}

// ---------------- shared helpers for wave-per-node kernels ----------------

// copy a packed 64KB W (8192 float2) into LDS, fully coalesced float4
__device__ __forceinline__ void stage_pk(const float2* __restrict__ Wp, float2* __restrict__ W2) {
    const float4* s = (const float4*)Wp;
    float4* d = (float4*)W2;
    for (int t = threadIdx.x; t < 4096; t += 256) d[t] = s[t];
}

template <bool MERGE>
__device__ __forceinline__ const float* resolve_row(const float* __restrict__ base,
                                                    const float* __restrict__ tmp,
                                                    const int* __restrict__ clsidx,
                                                    int mcls, int s) {
    if (MERGE) {
        int cc = clsidx[s];
        if ((cc >> 16) == mcls && (cc & 0xFFFF) < CAP) return tmp + (size_t)(cc & 0xFFFF) * DIM;
    }
    return base + (size_t)s * DIM;
}

// wave gathers sum over in-edges of relu(row(src) @ W2 + b); 2-edge unroll
template <bool MERGE>
__device__ __forceinline__ void gather_node(const float* __restrict__ hs,
                                            const float* __restrict__ tmp,
                                            const int* __restrict__ clsidx, int mcls,
                                            const float2* __restrict__ W2,
                                            float bj0, float bj1,
                                            const int* __restrict__ csr_src,
                                            int e0, int e1, int lane,
                                            float& acc0, float& acc1) {
    for (int p = e0; p < e1; p += 2) {
        const bool two = (p + 1 < e1);
        const int s0 = csr_src[p];
        const int s1 = two ? csr_src[p + 1] : s0;
        const float* r0 = resolve_row<MERGE>(hs, tmp, clsidx, mcls, s0);
        const float* r1 = resolve_row<MERGE>(hs, tmp, clsidx, mcls, s1);
        float a00 = r0[lane], a01 = r0[lane + 64];
        float a10 = r1[lane], a11 = r1[lane + 64];
        float m00 = bj0, m01 = bj1, m10 = bj0, m11 = bj1;
#pragma unroll 8
        for (int k = 0; k < 64; k++) {
            float2 w = W2[k * 64 + lane];
            float v0 = __shfl(a00, k, 64);
            float v1 = __shfl(a10, k, 64);
            m00 = fmaf(v0, w.x, m00); m01 = fmaf(v0, w.y, m01);
            m10 = fmaf(v1, w.x, m10); m11 = fmaf(v1, w.y, m11);
        }
#pragma unroll 8
        for (int k = 0; k < 64; k++) {
            float2 w = W2[(k + 64) * 64 + lane];
            float v0 = __shfl(a01, k, 64);
            float v1 = __shfl(a11, k, 64);
            m00 = fmaf(v0, w.x, m00); m01 = fmaf(v0, w.y, m01);
            m10 = fmaf(v1, w.x, m10); m11 = fmaf(v1, w.y, m11);
        }
        acc0 += fmaxf(m00, 0.f);
        acc1 += fmaxf(m01, 0.f);
        if (two) { acc0 += fmaxf(m10, 0.f); acc1 += fmaxf(m11, 0.f); }
    }
}

// ---------------- level-stage kernels (packed-W staging) ----------------

// AND stage: commit tmpN(cNp)->hs ; agg = gather(as_w, merged w/ tmpN) ;
//            tmpA[idx] = relu( cat[hs[node], agg] @ ua_w + ua_b )
template <bool MERGE>
__global__ __launch_bounds__(256) void and_stage_kernel(
        float* __restrict__ hs, const float* __restrict__ tmpN, float* __restrict__ tmpA,
        const int* __restrict__ offs, const int* __restrict__ csr_src,
        const int* __restrict__ nlist, const int* __restrict__ ncnt,
        const int* __restrict__ clsidx, const float2* __restrict__ wpack,
        const float* __restrict__ as_b, const float* __restrict__ ua_b,
        int cA, int cNp, int n) {
    const int cnt = min(ncnt[cA], CAP);
    const int cntp = MERGE ? min(ncnt[cNp], CAP) : 0;
    const int lim = max(cnt, cntp);
    if ((int)blockIdx.x * 4 >= lim) return;
    __shared__ float2 W2[128 * 64];
    const int lane = threadIdx.x & 63;
    const int gslot = (blockIdx.x << 2) | (threadIdx.x >> 6);
    stage_pk(wpack + AS_OFF, W2);
    if (MERGE) {
        for (int idx = gslot; idx < cntp; idx += NSLOT) {
            const int node = nlist[cNp * n + idx];
            hs[(size_t)node * DIM + lane] = tmpN[(size_t)idx * DIM + lane];
            hs[(size_t)node * DIM + lane + 64] = tmpN[(size_t)idx * DIM + lane + 64];
        }
    }
    __syncthreads();
    const float bj_as0 = as_b[lane], bj_as1 = as_b[lane + 64];
    float ag0[2] = {0.f, 0.f}, ag1[2] = {0.f, 0.f};
    float h0[2] = {0.f, 0.f}, h1[2] = {0.f, 0.f};
    bool act[2];
#pragma unroll
    for (int it = 0; it < 2; it++) {
        const int idx = gslot + it * NSLOT;
        act[it] = idx < cnt;
        if (act[it]) {
            const int nd = nlist[cA * n + idx];
            gather_node<MERGE>(hs, tmpN, clsidx, cNp, W2, bj_as0, bj_as1, csr_src,
                               offs[nd], offs[nd + 1], lane, ag0[it], ag1[it]);
            h0[it] = hs[(size_t)nd * DIM + lane];
            h1[it] = hs[(size_t)nd * DIM + lane + 64];
        }
    }
    float u0[2], u1[2];
    u0[0] = ua_b[lane]; u1[0] = ua_b[lane + 64];
    u0[1] = u0[0]; u1[1] = u1[0];
    __syncthreads();
    stage_pk(wpack + UA_OFF, W2);          // rows 0..127 (hs half)
    __syncthreads();
#pragma unroll
    for (int it = 0; it < 2; it++) {
        if (!act[it]) continue;
#pragma unroll 8
        for (int k = 0; k < 64; k++) {
            float2 w = W2[k * 64 + lane];
            float v = __shfl(h0[it], k, 64);
            u0[it] = fmaf(v, w.x, u0[it]); u1[it] = fmaf(v, w.y, u1[it]);
        }
#pragma unroll 8
        for (int k = 0; k < 64; k++) {
            float2 w = W2[(k + 64) * 64 + lane];
            float v = __shfl(h1[it], k, 64);
            u0[it] = fmaf(v, w.x, u0[it]); u1[it] = fmaf(v, w.y, u1[it]);
        }
    }
    __syncthreads();
    stage_pk(wpack + UA_OFF + 8192, W2);   // rows 128..255 (agg half)
    __syncthreads();
#pragma unroll
    for (int it = 0; it < 2; it++) {
        if (!act[it]) continue;
#pragma unroll 8
        for (int k = 0; k < 64; k++) {
            float2 w = W2[k * 64 + lane];
            float v = __shfl(ag0[it], k, 64);
            u0[it] = fmaf(v, w.x, u0[it]); u1[it] = fmaf(v, w.y, u1[it]);
        }
#pragma unroll 8
        for (int k = 0; k < 64; k++) {
            float2 w = W2[(k + 64) * 64 + lane];
            float v = __shfl(ag1[it], k, 64);
            u0[it] = fmaf(v, w.x, u0[it]); u1[it] = fmaf(v, w.y, u1[it]);
        }
        const int idx = gslot + it * NSLOT;
        tmpA[(size_t)idx * DIM + lane] = fmaxf(u0[it], 0.f);
        tmpA[(size_t)idx * DIM + lane + 64] = fmaxf(u1[it], 0.f);
    }
}

// NOT stage: commit tmpA(cA)->hs ; agg = gather(ns_w, merged w/ tmpA) ;
//            tmpN[idx] = tanh( agg @ un_w + un_b )
__global__ __launch_bounds__(256) void not_stage_kernel(
        float* __restrict__ hs, const float* __restrict__ tmpA, float* __restrict__ tmpN,
        const int* __restrict__ offs, const int* __restrict__ csr_src,
        const int* __restrict__ nlist, const int* __restrict__ ncnt,
        const int* __restrict__ clsidx, const float2* __restrict__ wpack,
        const float* __restrict__ ns_b, const float* __restrict__ un_b,
        int cA, int cN, int n) {
    const int cnt = min(ncnt[cN], CAP);
    const int cntA = min(ncnt[cA], CAP);
    const int lim = max(cnt, cntA);
    if ((int)blockIdx.x * 4 >= lim) return;
    __shared__ float2 W2[128 * 64];
    const int lane = threadIdx.x & 63;
    const int gslot = (blockIdx.x << 2) | (threadIdx.x >> 6);
    stage_pk(wpack + NS_OFF, W2);
    for (int idx = gslot; idx < cntA; idx += NSLOT) {
        const int node = nlist[cA * n + idx];
        hs[(size_t)node * DIM + lane] = tmpA[(size_t)idx * DIM + lane];
        hs[(size_t)node * DIM + lane + 64] = tmpA[(size_t)idx * DIM + lane + 64];
    }
    __syncthreads();
    const float bj_ns0 = ns_b[lane], bj_ns1 = ns_b[lane + 64];
    float ag0[2] = {0.f, 0.f}, ag1[2] = {0.f, 0.f};
    bool act[2];
#pragma unroll
    for (int it = 0; it < 2; it++) {
        const int idx = gslot + it * NSLOT;
        act[it] = idx < cnt;
        if (act[it]) {
            const int nd = nlist[cN * n + idx];
            gather_node<true>(hs, tmpA, clsidx, cA, W2, bj_ns0, bj_ns1, csr_src,
                              offs[nd], offs[nd + 1], lane, ag0[it], ag1[it]);
        }
    }
    float u0[2], u1[2];
    u0[0] = un_b[lane]; u1[0] = un_b[lane + 64];
    u0[1] = u0[0]; u1[1] = u1[0];
    __syncthreads();
    stage_pk(wpack + UN_OFF, W2);
    __syncthreads();
#pragma unroll
    for (int it = 0; it < 2; it++) {
        if (!act[it]) continue;
#pragma unroll 8
        for (int k = 0; k < 64; k++) {
            float2 w = W2[k * 64 + lane];
            float v = __shfl(ag0[it], k, 64);
            u0[it] = fmaf(v, w.x, u0[it]); u1[it] = fmaf(v, w.y, u1[it]);
        }
#pragma unroll 8
        for (int k = 0; k < 64; k++) {
            float2 w = W2[(k + 64) * 64 + lane];
            float v = __shfl(ag1[it], k, 64);
            u0[it] = fmaf(v, w.x, u0[it]); u1[it] = fmaf(v, w.y, u1[it]);
        }
        const int idx = gslot + it * NSLOT;
        tmpN[(size_t)idx * DIM + lane] = tanhf(u0[it]);
        tmpN[(size_t)idx * DIM + lane + 64] = tanhf(u1[it]);
    }
}

// final commit of last level's tmpN -> hs
__global__ __launch_bounds__(256) void commit_kernel(float* __restrict__ hs,
                                                     const float* __restrict__ tmp,
                                                     const int* __restrict__ nlist,
                                                     const int* __restrict__ ncnt,
                                                     int c, int n) {
    const int lane = threadIdx.x & 63;
    const int gslot = (blockIdx.x << 2) | (threadIdx.x >> 6);
    const int cnt = min(ncnt[c], CAP);
    for (int idx = gslot; idx < cnt; idx += NSLOT) {
        const int node = nlist[c * n + idx];
        hs[(size_t)node * DIM + lane] = tmp[(size_t)idx * DIM + lane];
        hs[(size_t)node * DIM + lane + 64] = tmp[(size_t)idx * DIM + lane + 64];
    }
}

// ---------------- decoder as gather (wave per node, deterministic) ----------------
__global__ __launch_bounds__(256) void dec_gather_kernel(const float* __restrict__ zs,
                                                         const float* __restrict__ zt,
                                                         const int* __restrict__ offs,
                                                         const int* __restrict__ csr_src,
                                                         float* __restrict__ hf_out, int n) {
    int w = threadIdx.x >> 6, lane = threadIdx.x & 63;
    for (int node = blockIdx.x * 4 + w; node < n; node += gridDim.x * 4) {
        float b0 = zt[(size_t)node * DIM + lane];
        float b1 = zt[(size_t)node * DIM + 64 + lane];
        float acc0 = 0.f, acc1 = 0.f;
        int e1 = offs[node + 1];
        for (int p = offs[node]; p < e1; p++) {
            int s = csr_src[p];
            float a0 = zs[(size_t)s * DIM + lane];
            float a1 = zs[(size_t)s * DIM + 64 + lane];
            float pd = a0 * b0 + a1 * b1;
#pragma unroll
            for (int off = 32; off > 0; off >>= 1) pd += __shfl_xor(pd, off, 64);
            float wg = 1.f / (1.f + __expf(-pd));
            acc0 += wg * a0;
            acc1 += wg * a1;
        }
        hf_out[(size_t)node * DIM + lane] = acc0;
        hf_out[(size_t)node * DIM + 64 + lane] = acc1;
    }
}

extern "C" void kernel_launch(void* const* d_in, const int* in_sizes, int n_in,
                              void* d_out, int out_size, void* d_ws, size_t ws_size,
                              hipStream_t stream) {
    const float* hs_init = (const float*)d_in[0];
    const int* ei = (const int*)d_in[1];
    const int* gate = (const int*)d_in[2];
    const int* level = (const int*)d_in[3];
    const float* gcn_w = (const float*)d_in[4];
    const float* gcn_b = (const float*)d_in[5];
    const float* mu_w = (const float*)d_in[6];
    const float* mu_b = (const float*)d_in[7];
    // ls_w/ls_b (8,9) dead (eval mode); af/nf (14..17) dead (level-loop hf never feeds hs;
    // decoder rebuilds hf from hs alone).
    const float* as_w = (const float*)d_in[10];
    const float* as_b = (const float*)d_in[11];
    const float* ns_w = (const float*)d_in[12];
    const float* ns_b = (const float*)d_in[13];
    const float* ua_w = (const float*)d_in[18];
    const float* ua_b = (const float*)d_in[19];
    const float* un_w = (const float*)d_in[20];
    const float* un_b = (const float*)d_in[21];
    const float* dec_ws_w = (const float*)d_in[22];
    const float* dec_wt_w = (const float*)d_in[23];

    const int n = in_sizes[0] / DIM;  // 32768
    const int E = in_sizes[1] / 2;    // 65536
    const int* srcv = ei;
    const int* dstv = ei + E;

    float* hs = (float*)d_out;             // [n, DIM]
    float* hf_out = hs + (size_t)n * DIM;  // [n, DIM]

    char* wp = (char*)d_ws;
    float* x = (float*)wp;      wp += (size_t)n * DIM * 4;     // gcn tmp, later zs
    float* x2 = (float*)wp;     wp += (size_t)n * DIM * 4;     // gcn tmp, later zt
    float* tmpA = (float*)wp;   wp += (size_t)CAP * DIM * 4;   // AND-update staging
    float* tmpN = (float*)wp;   wp += (size_t)CAP * DIM * 4;   // NOT-update staging
    float2* wpack = (float2*)wp; wp += (size_t)PACK_TOTAL * 8; // packed stage weights
    char* small0 = wp;
    int* degi = (int*)wp;   wp += (size_t)n * 4;
    int* cursor = (int*)wp; wp += (size_t)n * 4;
    int* ncnt = (int*)wp;   wp += 16 * 4;
    size_t small_bytes = (size_t)(wp - small0);
    int* bsum = (int*)wp;    wp += 64 * 4;
    int* offs = (int*)wp;    wp += (size_t)(n + 1) * 4;
    int* csr_src = (int*)wp; wp += (size_t)E * 4;
    int* nlist = (int*)wp;   wp += (size_t)16 * n * 4;
    int* clsidx = (int*)wp;  wp += (size_t)n * 4;
    float* dis = (float*)wp; wp += (size_t)n * 4;
    float* inv = (float*)wp; wp += (size_t)n * 4;

    hipMemsetAsync(small0, 0, small_bytes, stream);
    hipMemsetAsync(clsidx, 0xFF, (size_t)n * 4, stream);

    pack_kernel<<<(PACK_TOTAL + 255) / 256, 256, 0, stream>>>(as_w, ua_w, ns_w, un_w, wpack);
    deg_count_kernel<<<(E + 255) / 256, 256, 0, stream>>>(dstv, degi, E);
    deg_finalize_kernel<<<(n + 255) / 256, 256, 0, stream>>>(degi, dis, inv, n);
    build_node_lists_kernel<<<(n + 255) / 256, 256, 0, stream>>>(gate, level, nlist, ncnt, clsidx, n);
    scan1_kernel<<<n / 1024, 1024, 0, stream>>>(degi, offs, bsum);
    scan2_kernel<<<1, 64, 0, stream>>>(bsum, n / 1024);
    scan3_kernel<<<n / 1024, 1024, 0, stream>>>(offs, bsum, n);
    csr_fill_kernel<<<(E + 255) / 256, 256, 0, stream>>>(srcv, dstv, offs, cursor, csr_src, E);

    // --- GCN encoder (split: dense GEMMs at high occupancy, gather separate) ---
    mm_kernel<0><<<n / 64, 256, 0, stream>>>(hs_init, gcn_w, nullptr, x, n);
    gcn_gather_kernel<<<4096, 256, 0, stream>>>(x, dis, inv, gcn_b, offs, csr_src, x2, n);
    mm_kernel<1><<<n / 64, 256, 0, stream>>>(x2, mu_w, mu_b, hs, n);  // hs = mu

    // --- level loop: 2 launches/level, 1 final commit ---
    for (int l = 1; l <= NLEV; l++) {
        const int cA = l - 1;
        const int cN = NLEV + l - 1;
        const int cNp = NLEV + l - 2;
        if (l == 1)
            and_stage_kernel<false><<<NB_STAGE, 256, 0, stream>>>(
                hs, tmpN, tmpA, offs, csr_src, nlist, ncnt, clsidx, wpack,
                as_b, ua_b, cA, -9, n);
        else
            and_stage_kernel<true><<<NB_STAGE, 256, 0, stream>>>(
                hs, tmpN, tmpA, offs, csr_src, nlist, ncnt, clsidx, wpack,
                as_b, ua_b, cA, cNp, n);
        not_stage_kernel<<<NB_STAGE, 256, 0, stream>>>(
            hs, tmpA, tmpN, offs, csr_src, nlist, ncnt, clsidx, wpack,
            ns_b, un_b, cA, cN, n);
    }
    commit_kernel<<<NB_STAGE, 256, 0, stream>>>(hs, tmpN, nlist, ncnt, 2 * NLEV - 1, n);

    // --- decoder: zs/zt dense (shared tile), then weighted gather ---
    float* zs = x;
    float* zt = x2;
    mm2_kernel<<<n / 32, 256, 0, stream>>>(hs, dec_ws_w, dec_wt_w, zs, zt, n);
    dec_gather_kernel<<<4096, 256, 0, stream>>>(zs, zt, offs, csr_src, hf_out, n);
}

// Round 10
// 699.726 us; speedup vs baseline: 1.1112x; 1.0028x over previous
//
#include <hip/hip_runtime.h>

#define DIM 128
#define NLEV 8
#define NB_STAGE 512           // stage-kernel grid; 4 waves/block -> 2048 wave-slots
#define NSLOT (NB_STAGE * 4)
#define CAP (2 * NSLOT)        // max nodes per class handled (expected ~1213)

// packed-weight offsets (float2 units): [k][jl] -> (W[k][jl], W[k][jl+64])
#define AS_OFF 0
#define UA_OFF 8192            // 256 rows -> 16384
#define NS_OFF 24576
#define UN_OFF 32768
#define PACK_TOTAL 40960

__device__ __forceinline__ int cls_of(int g, int l) {
    if (l < 1 || l > NLEV) return -1;
    if (g == 1) return l - 1;
    if (g == 2) return NLEV + (l - 1);
    return -1;
}

// ---------------- prep kernels ----------------

__global__ void deg_count_kernel(const int* __restrict__ dstv, int* __restrict__ degi, int E) {
    int i = blockIdx.x * blockDim.x + threadIdx.x;
    if (i < E) atomicAdd(&degi[dstv[i]], 1);
}

// pack 4 stage weight matrices into float2-paired layout for fast LDS staging
__global__ void pack_kernel(const float* __restrict__ as_w, const float* __restrict__ ua_w,
                            const float* __restrict__ ns_w, const float* __restrict__ un_w,
                            float2* __restrict__ wpack) {
    int i = blockIdx.x * 256 + threadIdx.x;
    if (i >= PACK_TOTAL) return;
    const float* src;
    int local;
    if (i < UA_OFF)      { src = as_w; local = i; }
    else if (i < NS_OFF) { src = ua_w; local = i - UA_OFF; }
    else if (i < UN_OFF) { src = ns_w; local = i - NS_OFF; }
    else                 { src = un_w; local = i - UN_OFF; }
    int k = local >> 6, jl = local & 63;
    wpack[i] = make_float2(src[k * DIM + jl], src[k * DIM + jl + 64]);
}

// b' = gcn_b @ mu_w + mu_b   (folded GCN bias)
__global__ __launch_bounds__(DIM) void bprime_kernel(const float* __restrict__ gcn_b,
                                                     const float* __restrict__ mu_w,
                                                     const float* __restrict__ mu_b,
                                                     float* __restrict__ bp) {
    const int j = threadIdx.x;
    float acc = mu_b[j];
    for (int k = 0; k < DIM; k++) acc = fmaf(gcn_b[k], mu_w[k * DIM + j], acc);
    bp[j] = acc;
}

// ---- scan1 (+ fused deg finalize): degi -> per-block exclusive scan, dis/inv ----
__global__ __launch_bounds__(1024) void scan1_kernel(const int* __restrict__ degi,
                                                     int* __restrict__ offs,
                                                     int* __restrict__ bsum,
                                                     float* __restrict__ dis,
                                                     float* __restrict__ inv) {
    __shared__ int sh[1024];
    const int gid = blockIdx.x * 1024 + threadIdx.x;
    const int v = degi[gid];
    {
        float d = (float)v + 1.0f;
        dis[gid] = rsqrtf(d);
        inv[gid] = 1.0f / d;
    }
    sh[threadIdx.x] = v;
    __syncthreads();
    for (int off = 1; off < 1024; off <<= 1) {
        int t = (threadIdx.x >= off) ? sh[threadIdx.x - off] : 0;
        __syncthreads();
        sh[threadIdx.x] += t;
        __syncthreads();
    }
    offs[gid] = sh[threadIdx.x] - v;
    if (threadIdx.x == 1023) bsum[blockIdx.x] = sh[1023];
}

__global__ void scan2_kernel(int* __restrict__ bsum, int nb) {
    const int lane = threadIdx.x & 63;
    const int orig = (lane < nb) ? bsum[lane] : 0;
    int v = orig;
#pragma unroll
    for (int off = 1; off < 64; off <<= 1) {
        int t = __shfl_up(v, off, 64);
        if (lane >= off) v += t;
    }
    if (lane < nb) bsum[lane] = v - orig;
    if (lane == nb - 1) bsum[nb] = v;
}

__global__ __launch_bounds__(1024) void scan3_kernel(int* __restrict__ offs,
                                                     const int* __restrict__ bsum, int n) {
    const int gid = blockIdx.x * 1024 + threadIdx.x;
    offs[gid] += bsum[blockIdx.x];
    if (gid == n - 1) offs[n] = bsum[gridDim.x];
}

__global__ void csr_fill_kernel(const int* __restrict__ srcv, const int* __restrict__ dstv,
                                const int* __restrict__ offs, int* __restrict__ cursor,
                                int* __restrict__ csr_src, int E) {
    int i = blockIdx.x * blockDim.x + threadIdx.x;
    if (i >= E) return;
    int d = dstv[i];
    int pos = offs[d] + atomicAdd(&cursor[d], 1);
    csr_src[pos] = srcv[i];
}

// class lists + per-node packed (cls<<16)|idx lookup (clsidx pre-memset to -1)
__global__ __launch_bounds__(256) void build_node_lists_kernel(const int* __restrict__ gate,
                                                               const int* __restrict__ level,
                                                               int* __restrict__ nlist,
                                                               int* __restrict__ ncnt,
                                                               int* __restrict__ clsidx, int n) {
    __shared__ int lcnt[16];
    __shared__ int lbase[16];
    int t = threadIdx.x;
    int i = blockIdx.x * 256 + t;
    if (t < 16) lcnt[t] = 0;
    __syncthreads();
    int c = -1, lpos = 0;
    if (i < n) {
        c = cls_of(gate[i], level[i]);
        if (c >= 0) lpos = atomicAdd(&lcnt[c], 1);
    }
    __syncthreads();
    if (t < 16 && lcnt[t] > 0) lbase[t] = atomicAdd(&ncnt[t], lcnt[t]);
    __syncthreads();
    if (c >= 0) {
        int idx = lbase[c] + lpos;
        nlist[c * n + idx] = i;
        clsidx[i] = (c << 16) | idx;
    }
}

// ---------------- dense matmul: LDS tile, 64 rows/block, W-prefetch ----------------
template <int BIAS>
__global__ __launch_bounds__(256) void mm_kernel(const float* __restrict__ in0,
                                                 const float* __restrict__ W,
                                                 const float* __restrict__ b,
                                                 float* __restrict__ out, int n) {
    const int R = 64;
    __shared__ float tile[R * DIM];
    const size_t row0 = (size_t)blockIdx.x * R;
    for (int t = threadIdx.x; t < R * DIM / 4; t += 256)
        ((float4*)tile)[t] = ((const float4*)(in0 + row0 * DIM))[t];
    __syncthreads();
    const int g = threadIdx.x >> 7;   // row-half 0/1 (32 rows each)
    const int j = threadIdx.x & 127;  // output column
    float acc[32];
#pragma unroll
    for (int r = 0; r < 32; r++) acc[r] = 0.f;
    const float* tb = tile + (g * 32) * DIM;
    float w0 = W[0 * DIM + j], w1 = W[1 * DIM + j], w2 = W[2 * DIM + j], w3 = W[3 * DIM + j];
    for (int k = 0; k < DIM; k += 4) {
        const int kn = (k + 4 < DIM) ? (k + 4) : 0;  // prefetch next iteration's W
        const float nw0 = W[(kn + 0) * DIM + j];
        const float nw1 = W[(kn + 1) * DIM + j];
        const float nw2 = W[(kn + 2) * DIM + j];
        const float nw3 = W[(kn + 3) * DIM + j];
#pragma unroll
        for (int r = 0; r < 32; r++) {
            const float4 a = *reinterpret_cast<const float4*>(tb + r * DIM + k);
            acc[r] = fmaf(a.x, w0, acc[r]);
            acc[r] = fmaf(a.y, w1, acc[r]);
            acc[r] = fmaf(a.z, w2, acc[r]);
            acc[r] = fmaf(a.w, w3, acc[r]);
        }
        w0 = nw0; w1 = nw1; w2 = nw2; w3 = nw3;
    }
    float bias = BIAS ? b[j] : 0.f;
#pragma unroll
    for (int r = 0; r < 32; r++) out[(row0 + g * 32 + r) * DIM + j] = acc[r] + bias;
}

// fused decoder matmul: zs = in0 @ Ws, zt = in0 @ Wt (shared tile, k-quad, W-prefetch)
__global__ __launch_bounds__(256) void mm2_kernel(const float* __restrict__ in0,
                                                  const float* __restrict__ Ws,
                                                  const float* __restrict__ Wt,
                                                  float* __restrict__ zs,
                                                  float* __restrict__ zt, int n) {
    const int R = 32;
    __shared__ float tile[R * DIM];
    const size_t row0 = (size_t)blockIdx.x * R;
    for (int t = threadIdx.x; t < R * DIM / 4; t += 256)
        ((float4*)tile)[t] = ((const float4*)(in0 + row0 * DIM))[t];
    __syncthreads();
    const int g = threadIdx.x >> 7;
    const int j = threadIdx.x & 127;
    float accs[16], acct[16];
#pragma unroll
    for (int r = 0; r < 16; r++) { accs[r] = 0.f; acct[r] = 0.f; }
    const float* tb = tile + (g * 16) * DIM;
    float s0 = Ws[0 * DIM + j], s1 = Ws[1 * DIM + j], s2 = Ws[2 * DIM + j], s3 = Ws[3 * DIM + j];
    float t0 = Wt[0 * DIM + j], t1 = Wt[1 * DIM + j], t2 = Wt[2 * DIM + j], t3 = Wt[3 * DIM + j];
    for (int k = 0; k < DIM; k += 4) {
        const int kn = (k + 4 < DIM) ? (k + 4) : 0;  // prefetch
        const float ps0 = Ws[(kn + 0) * DIM + j];
        const float ps1 = Ws[(kn + 1) * DIM + j];
        const float ps2 = Ws[(kn + 2) * DIM + j];
        const float ps3 = Ws[(kn + 3) * DIM + j];
        const float pt0 = Wt[(kn + 0) * DIM + j];
        const float pt1 = Wt[(kn + 1) * DIM + j];
        const float pt2 = Wt[(kn + 2) * DIM + j];
        const float pt3 = Wt[(kn + 3) * DIM + j];
#pragma unroll
        for (int r = 0; r < 16; r++) {
            const float4 a = *reinterpret_cast<const float4*>(tb + r * DIM + k);  // 1 read, 8 FMA
            accs[r] = fmaf(a.x, s0, accs[r]);
            accs[r] = fmaf(a.y, s1, accs[r]);
            accs[r] = fmaf(a.z, s2, accs[r]);
            accs[r] = fmaf(a.w, s3, accs[r]);
            acct[r] = fmaf(a.x, t0, acct[r]);
            acct[r] = fmaf(a.y, t1, acct[r]);
            acct[r] = fmaf(a.z, t2, acct[r]);
            acct[r] = fmaf(a.w, t3, acct[r]);
        }
        s0 = ps0; s1 = ps1; s2 = ps2; s3 = ps3;
        t0 = pt0; t1 = pt1; t2 = pt2; t3 = pt3;
    }
#pragma unroll
    for (int r = 0; r < 16; r++) {
        zs[(row0 + g * 16 + r) * DIM + j] = accs[r];
        zt[(row0 + g * 16 + r) * DIM + j] = acct[r];
    }
}

// ---------------- GCN aggregate as gather (bias folded into b') ----------------
__global__ __launch_bounds__(256) void gcn_gather_kernel(const float* __restrict__ x,
                                                         const float* __restrict__ dis,
                                                         const float* __restrict__ inv,
                                                         const int* __restrict__ offs,
                                                         const int* __restrict__ csr_src,
                                                         float* __restrict__ y, int n) {
    int slot = threadIdx.x >> 7, j = threadIdx.x & 127;
    for (int node = blockIdx.x * 2 + slot; node < n; node += gridDim.x * 2) {
        float di = dis[node];
        float acc = inv[node] * x[(size_t)node * DIM + j];
        int e1 = offs[node + 1];
        for (int p = offs[node]; p < e1; p++) {
            int s = csr_src[p];
            acc += di * dis[s] * x[(size_t)s * DIM + j];
        }
        y[(size_t)node * DIM + j] = acc;
    }
}

// ---------------- shared helpers for wave-per-node kernels ----------------

// copy a packed 64KB W (8192 float2) into LDS, fully coalesced float4
__device__ __forceinline__ void stage_pk(const float2* __restrict__ Wp, float2* __restrict__ W2) {
    const float4* s = (const float4*)Wp;
    float4* d = (float4*)W2;
    for (int t = threadIdx.x; t < 4096; t += 256) d[t] = s[t];
}

template <bool MERGE>
__device__ __forceinline__ const float* resolve_row(const float* __restrict__ base,
                                                    const float* __restrict__ tmp,
                                                    const int* __restrict__ clsidx,
                                                    int mcls, int s) {
    if (MERGE) {
        int cc = clsidx[s];
        if ((cc >> 16) == mcls && (cc & 0xFFFF) < CAP) return tmp + (size_t)(cc & 0xFFFF) * DIM;
    }
    return base + (size_t)s * DIM;
}

// wave gathers sum over in-edges of relu(row(src) @ W2 + b); 2-edge unroll
template <bool MERGE>
__device__ __forceinline__ void gather_node(const float* __restrict__ hs,
                                            const float* __restrict__ tmp,
                                            const int* __restrict__ clsidx, int mcls,
                                            const float2* __restrict__ W2,
                                            float bj0, float bj1,
                                            const int* __restrict__ csr_src,
                                            int e0, int e1, int lane,
                                            float& acc0, float& acc1) {
    for (int p = e0; p < e1; p += 2) {
        const bool two = (p + 1 < e1);
        const int s0 = csr_src[p];
        const int s1 = two ? csr_src[p + 1] : s0;
        const float* r0 = resolve_row<MERGE>(hs, tmp, clsidx, mcls, s0);
        const float* r1 = resolve_row<MERGE>(hs, tmp, clsidx, mcls, s1);
        float a00 = r0[lane], a01 = r0[lane + 64];
        float a10 = r1[lane], a11 = r1[lane + 64];
        float m00 = bj0, m01 = bj1, m10 = bj0, m11 = bj1;
#pragma unroll 8
        for (int k = 0; k < 64; k++) {
            float2 w = W2[k * 64 + lane];
            float v0 = __shfl(a00, k, 64);
            float v1 = __shfl(a10, k, 64);
            m00 = fmaf(v0, w.x, m00); m01 = fmaf(v0, w.y, m01);
            m10 = fmaf(v1, w.x, m10); m11 = fmaf(v1, w.y, m11);
        }
#pragma unroll 8
        for (int k = 0; k < 64; k++) {
            float2 w = W2[(k + 64) * 64 + lane];
            float v0 = __shfl(a01, k, 64);
            float v1 = __shfl(a11, k, 64);
            m00 = fmaf(v0, w.x, m00); m01 = fmaf(v0, w.y, m01);
            m10 = fmaf(v1, w.x, m10); m11 = fmaf(v1, w.y, m11);
        }
        acc0 += fmaxf(m00, 0.f);
        acc1 += fmaxf(m01, 0.f);
        if (two) { acc0 += fmaxf(m10, 0.f); acc1 += fmaxf(m11, 0.f); }
    }
}

// ---------------- level-stage kernels (packed-W staging) ----------------

// AND stage: commit tmpN(cNp)->hs ; agg = gather(as_w, merged w/ tmpN) ;
//            tmpA[idx] = relu( cat[hs[node], agg] @ ua_w + ua_b )
template <bool MERGE>
__global__ __launch_bounds__(256) void and_stage_kernel(
        float* __restrict__ hs, const float* __restrict__ tmpN, float* __restrict__ tmpA,
        const int* __restrict__ offs, const int* __restrict__ csr_src,
        const int* __restrict__ nlist, const int* __restrict__ ncnt,
        const int* __restrict__ clsidx, const float2* __restrict__ wpack,
        const float* __restrict__ as_b, const float* __restrict__ ua_b,
        int cA, int cNp, int n) {
    const int cnt = min(ncnt[cA], CAP);
    const int cntp = MERGE ? min(ncnt[cNp], CAP) : 0;
    const int lim = max(cnt, cntp);
    if ((int)blockIdx.x * 4 >= lim) return;
    __shared__ float2 W2[128 * 64];
    const int lane = threadIdx.x & 63;
    const int gslot = (blockIdx.x << 2) | (threadIdx.x >> 6);
    stage_pk(wpack + AS_OFF, W2);
    if (MERGE) {
        for (int idx = gslot; idx < cntp; idx += NSLOT) {
            const int node = nlist[cNp * n + idx];
            hs[(size_t)node * DIM + lane] = tmpN[(size_t)idx * DIM + lane];
            hs[(size_t)node * DIM + lane + 64] = tmpN[(size_t)idx * DIM + lane + 64];
        }
    }
    __syncthreads();
    const float bj_as0 = as_b[lane], bj_as1 = as_b[lane + 64];
    float ag0[2] = {0.f, 0.f}, ag1[2] = {0.f, 0.f};
    float h0[2] = {0.f, 0.f}, h1[2] = {0.f, 0.f};
    bool act[2];
#pragma unroll
    for (int it = 0; it < 2; it++) {
        const int idx = gslot + it * NSLOT;
        act[it] = idx < cnt;
        if (act[it]) {
            const int nd = nlist[cA * n + idx];
            gather_node<MERGE>(hs, tmpN, clsidx, cNp, W2, bj_as0, bj_as1, csr_src,
                               offs[nd], offs[nd + 1], lane, ag0[it], ag1[it]);
            h0[it] = hs[(size_t)nd * DIM + lane];
            h1[it] = hs[(size_t)nd * DIM + lane + 64];
        }
    }
    float u0[2], u1[2];
    u0[0] = ua_b[lane]; u1[0] = ua_b[lane + 64];
    u0[1] = u0[0]; u1[1] = u1[0];
    __syncthreads();
    stage_pk(wpack + UA_OFF, W2);          // rows 0..127 (hs half)
    __syncthreads();
#pragma unroll
    for (int it = 0; it < 2; it++) {
        if (!act[it]) continue;
#pragma unroll 8
        for (int k = 0; k < 64; k++) {
            float2 w = W2[k * 64 + lane];
            float v = __shfl(h0[it], k, 64);
            u0[it] = fmaf(v, w.x, u0[it]); u1[it] = fmaf(v, w.y, u1[it]);
        }
#pragma unroll 8
        for (int k = 0; k < 64; k++) {
            float2 w = W2[(k + 64) * 64 + lane];
            float v = __shfl(h1[it], k, 64);
            u0[it] = fmaf(v, w.x, u0[it]); u1[it] = fmaf(v, w.y, u1[it]);
        }
    }
    __syncthreads();
    stage_pk(wpack + UA_OFF + 8192, W2);   // rows 128..255 (agg half)
    __syncthreads();
#pragma unroll
    for (int it = 0; it < 2; it++) {
        if (!act[it]) continue;
#pragma unroll 8
        for (int k = 0; k < 64; k++) {
            float2 w = W2[k * 64 + lane];
            float v = __shfl(ag0[it], k, 64);
            u0[it] = fmaf(v, w.x, u0[it]); u1[it] = fmaf(v, w.y, u1[it]);
        }
#pragma unroll 8
        for (int k = 0; k < 64; k++) {
            float2 w = W2[(k + 64) * 64 + lane];
            float v = __shfl(ag1[it], k, 64);
            u0[it] = fmaf(v, w.x, u0[it]); u1[it] = fmaf(v, w.y, u1[it]);
        }
        const int idx = gslot + it * NSLOT;
        tmpA[(size_t)idx * DIM + lane] = fmaxf(u0[it], 0.f);
        tmpA[(size_t)idx * DIM + lane + 64] = fmaxf(u1[it], 0.f);
    }
}

// NOT stage: commit tmpA(cA)->hs ; agg = gather(ns_w, merged w/ tmpA) ;
//            tmpN[idx] = tanh( agg @ un_w + un_b )
__global__ __launch_bounds__(256) void not_stage_kernel(
        float* __restrict__ hs, const float* __restrict__ tmpA, float* __restrict__ tmpN,
        const int* __restrict__ offs, const int* __restrict__ csr_src,
        const int* __restrict__ nlist, const int* __restrict__ ncnt,
        const int* __restrict__ clsidx, const float2* __restrict__ wpack,
        const float* __restrict__ ns_b, const float* __restrict__ un_b,
        int cA, int cN, int n) {
    const int cnt = min(ncnt[cN], CAP);
    const int cntA = min(ncnt[cA], CAP);
    const int lim = max(cnt, cntA);
    if ((int)blockIdx.x * 4 >= lim) return;
    __shared__ float2 W2[128 * 64];
    const int lane = threadIdx.x & 63;
    const int gslot = (blockIdx.x << 2) | (threadIdx.x >> 6);
    stage_pk(wpack + NS_OFF, W2);
    for (int idx = gslot; idx < cntA; idx += NSLOT) {
        const int node = nlist[cA * n + idx];
        hs[(size_t)node * DIM + lane] = tmpA[(size_t)idx * DIM + lane];
        hs[(size_t)node * DIM + lane + 64] = tmpA[(size_t)idx * DIM + lane + 64];
    }
    __syncthreads();
    const float bj_ns0 = ns_b[lane], bj_ns1 = ns_b[lane + 64];
    float ag0[2] = {0.f, 0.f}, ag1[2] = {0.f, 0.f};
    bool act[2];
#pragma unroll
    for (int it = 0; it < 2; it++) {
        const int idx = gslot + it * NSLOT;
        act[it] = idx < cnt;
        if (act[it]) {
            const int nd = nlist[cN * n + idx];
            gather_node<true>(hs, tmpA, clsidx, cA, W2, bj_ns0, bj_ns1, csr_src,
                              offs[nd], offs[nd + 1], lane, ag0[it], ag1[it]);
        }
    }
    float u0[2], u1[2];
    u0[0] = un_b[lane]; u1[0] = un_b[lane + 64];
    u0[1] = u0[0]; u1[1] = u1[0];
    __syncthreads();
    stage_pk(wpack + UN_OFF, W2);
    __syncthreads();
#pragma unroll
    for (int it = 0; it < 2; it++) {
        if (!act[it]) continue;
#pragma unroll 8
        for (int k = 0; k < 64; k++) {
            float2 w = W2[k * 64 + lane];
            float v = __shfl(ag0[it], k, 64);
            u0[it] = fmaf(v, w.x, u0[it]); u1[it] = fmaf(v, w.y, u1[it]);
        }
#pragma unroll 8
        for (int k = 0; k < 64; k++) {
            float2 w = W2[(k + 64) * 64 + lane];
            float v = __shfl(ag1[it], k, 64);
            u0[it] = fmaf(v, w.x, u0[it]); u1[it] = fmaf(v, w.y, u1[it]);
        }
        const int idx = gslot + it * NSLOT;
        tmpN[(size_t)idx * DIM + lane] = tanhf(u0[it]);
        tmpN[(size_t)idx * DIM + lane + 64] = tanhf(u1[it]);
    }
}

// final commit of last level's tmpN -> hs
__global__ __launch_bounds__(256) void commit_kernel(float* __restrict__ hs,
                                                     const float* __restrict__ tmp,
                                                     const int* __restrict__ nlist,
                                                     const int* __restrict__ ncnt,
                                                     int c, int n) {
    const int lane = threadIdx.x & 63;
    const int gslot = (blockIdx.x << 2) | (threadIdx.x >> 6);
    const int cnt = min(ncnt[c], CAP);
    for (int idx = gslot; idx < cnt; idx += NSLOT) {
        const int node = nlist[c * n + idx];
        hs[(size_t)node * DIM + lane] = tmp[(size_t)idx * DIM + lane];
        hs[(size_t)node * DIM + lane + 64] = tmp[(size_t)idx * DIM + lane + 64];
    }
}

// ---------------- decoder as gather (wave per node, deterministic) ----------------
__global__ __launch_bounds__(256) void dec_gather_kernel(const float* __restrict__ zs,
                                                         const float* __restrict__ zt,
                                                         const int* __restrict__ offs,
                                                         const int* __restrict__ csr_src,
                                                         float* __restrict__ hf_out, int n) {
    int w = threadIdx.x >> 6, lane = threadIdx.x & 63;
    for (int node = blockIdx.x * 4 + w; node < n; node += gridDim.x * 4) {
        float b0 = zt[(size_t)node * DIM + lane];
        float b1 = zt[(size_t)node * DIM + 64 + lane];
        float acc0 = 0.f, acc1 = 0.f;
        int e1 = offs[node + 1];
        for (int p = offs[node]; p < e1; p++) {
            int s = csr_src[p];
            float a0 = zs[(size_t)s * DIM + lane];
            float a1 = zs[(size_t)s * DIM + 64 + lane];
            float pd = a0 * b0 + a1 * b1;
#pragma unroll
            for (int off = 32; off > 0; off >>= 1) pd += __shfl_xor(pd, off, 64);
            float wg = 1.f / (1.f + __expf(-pd));
            acc0 += wg * a0;
            acc1 += wg * a1;
        }
        hf_out[(size_t)node * DIM + lane] = acc0;
        hf_out[(size_t)node * DIM + 64 + lane] = acc1;
    }
}

extern "C" void kernel_launch(void* const* d_in, const int* in_sizes, int n_in,
                              void* d_out, int out_size, void* d_ws, size_t ws_size,
                              hipStream_t stream) {
    const float* hs_init = (const float*)d_in[0];
    const int* ei = (const int*)d_in[1];
    const int* gate = (const int*)d_in[2];
    const int* level = (const int*)d_in[3];
    const float* gcn_w = (const float*)d_in[4];
    const float* gcn_b = (const float*)d_in[5];
    const float* mu_w = (const float*)d_in[6];
    const float* mu_b = (const float*)d_in[7];
    // ls_w/ls_b (8,9) dead (eval mode); af/nf (14..17) dead (level-loop hf never feeds hs;
    // decoder rebuilds hf from hs alone).
    const float* as_w = (const float*)d_in[10];
    const float* as_b = (const float*)d_in[11];
    const float* ns_w = (const float*)d_in[12];
    const float* ns_b = (const float*)d_in[13];
    const float* ua_w = (const float*)d_in[18];
    const float* ua_b = (const float*)d_in[19];
    const float* un_w = (const float*)d_in[20];
    const float* un_b = (const float*)d_in[21];
    const float* dec_ws_w = (const float*)d_in[22];
    const float* dec_wt_w = (const float*)d_in[23];

    const int n = in_sizes[0] / DIM;  // 32768
    const int E = in_sizes[1] / 2;    // 65536
    const int* srcv = ei;
    const int* dstv = ei + E;

    float* hs = (float*)d_out;             // [n, DIM]
    float* hf_out = hs + (size_t)n * DIM;  // [n, DIM]

    char* wp = (char*)d_ws;
    float* x = (float*)wp;      wp += (size_t)n * DIM * 4;     // gcn y, later zs
    float* x2 = (float*)wp;     wp += (size_t)n * DIM * 4;     // zt
    float* tmpA = (float*)wp;   wp += (size_t)CAP * DIM * 4;   // AND-update staging
    float* tmpN = (float*)wp;   wp += (size_t)CAP * DIM * 4;   // NOT-update staging
    float2* wpack = (float2*)wp; wp += (size_t)PACK_TOTAL * 8; // packed stage weights
    float* wprime = (float*)wp; wp += (size_t)DIM * DIM * 4;   // gcn_w @ mu_w
    float* bprime = (float*)wp; wp += (size_t)DIM * 4;         // gcn_b @ mu_w + mu_b
    char* small0 = wp;
    int* degi = (int*)wp;   wp += (size_t)n * 4;
    int* cursor = (int*)wp; wp += (size_t)n * 4;
    int* ncnt = (int*)wp;   wp += 16 * 4;
    size_t small_bytes = (size_t)(wp - small0);
    int* bsum = (int*)wp;    wp += 64 * 4;
    int* offs = (int*)wp;    wp += (size_t)(n + 1) * 4;
    int* csr_src = (int*)wp; wp += (size_t)E * 4;
    int* nlist = (int*)wp;   wp += (size_t)16 * n * 4;
    int* clsidx = (int*)wp;  wp += (size_t)n * 4;
    float* dis = (float*)wp; wp += (size_t)n * 4;
    float* inv = (float*)wp; wp += (size_t)n * 4;

    hipMemsetAsync(small0, 0, small_bytes, stream);
    hipMemsetAsync(clsidx, 0xFF, (size_t)n * 4, stream);

    // tiny precompute: W' = gcn_w @ mu_w (n=128 -> 2 blocks), b' = gcn_b @ mu_w + mu_b
    mm_kernel<0><<<2, 256, 0, stream>>>(gcn_w, mu_w, nullptr, wprime, DIM);
    bprime_kernel<<<1, DIM, 0, stream>>>(gcn_b, mu_w, mu_b, bprime);

    pack_kernel<<<(PACK_TOTAL + 255) / 256, 256, 0, stream>>>(as_w, ua_w, ns_w, un_w, wpack);
    deg_count_kernel<<<(E + 255) / 256, 256, 0, stream>>>(dstv, degi, E);
    build_node_lists_kernel<<<(n + 255) / 256, 256, 0, stream>>>(gate, level, nlist, ncnt, clsidx, n);
    scan1_kernel<<<n / 1024, 1024, 0, stream>>>(degi, offs, bsum, dis, inv);
    scan2_kernel<<<1, 64, 0, stream>>>(bsum, n / 1024);
    scan3_kernel<<<n / 1024, 1024, 0, stream>>>(offs, bsum, n);
    csr_fill_kernel<<<(E + 255) / 256, 256, 0, stream>>>(srcv, dstv, offs, cursor, csr_src, E);

    // --- GCN encoder, algebra-folded: hs = agg(hs_init) @ W' + b' ---
    gcn_gather_kernel<<<4096, 256, 0, stream>>>(hs_init, dis, inv, offs, csr_src, x, n);
    mm_kernel<1><<<n / 64, 256, 0, stream>>>(x, wprime, bprime, hs, n);

    // --- level loop: 2 launches/level, 1 final commit ---
    for (int l = 1; l <= NLEV; l++) {
        const int cA = l - 1;
        const int cN = NLEV + l - 1;
        const int cNp = NLEV + l - 2;
        if (l == 1)
            and_stage_kernel<false><<<NB_STAGE, 256, 0, stream>>>(
                hs, tmpN, tmpA, offs, csr_src, nlist, ncnt, clsidx, wpack,
                as_b, ua_b, cA, -9, n);
        else
            and_stage_kernel<true><<<NB_STAGE, 256, 0, stream>>>(
                hs, tmpN, tmpA, offs, csr_src, nlist, ncnt, clsidx, wpack,
                as_b, ua_b, cA, cNp, n);
        not_stage_kernel<<<NB_STAGE, 256, 0, stream>>>(
            hs, tmpA, tmpN, offs, csr_src, nlist, ncnt, clsidx, wpack,
            ns_b, un_b, cA, cN, n);
    }
    commit_kernel<<<NB_STAGE, 256, 0, stream>>>(hs, tmpN, nlist, ncnt, 2 * NLEV - 1, n);

    // --- decoder: zs/zt dense (shared tile, k-quad), then weighted gather ---
    float* zs = x;
    float* zt = x2;
    mm2_kernel<<<n / 32, 256, 0, stream>>>(hs, dec_ws_w, dec_wt_w, zs, zt, n);
    dec_gather_kernel<<<4096, 256, 0, stream>>>(zs, zt, offs, csr_src, hf_out, n);
}